// Round 8
// baseline (128.610 us; speedup 1.0000x reference)
//
#include <hip/hip_runtime.h>
#include <math.h>

#define Nn 65536

typedef short s16x8 __attribute__((ext_vector_type(8)));
typedef float f32x4 __attribute__((ext_vector_type(4)));
typedef unsigned int u32;

__device__ __forceinline__ unsigned short f2bf(float x) {
    u32 u = __float_as_uint(x);
    u += 0x7FFFu + ((u >> 16) & 1u);
    return (unsigned short)(u >> 16);
}

// argmax over row s of the 4x4 type_matching (first max wins, matches jnp.argmax)
__device__ __forceinline__ int best_t_for(const float* __restrict__ tm, int s, float* mOut) {
    float m = tm[s * 4];
    int am = 0;
#pragma unroll
    for (int j = 1; j < 4; ++j) {
        float v = tm[s * 4 + j];
        if (v > m) { m = v; am = j; }
    }
    if (mOut) *mOut = m;
    return am;
}

// ============ k_prepw: weight convert ONLY (96 blocks) ============
// fp32 [D][H] -> bf16 fragment-linear for the 12 live (s, best_t) matrices
__global__ void k_prepw(const float* __restrict__ tm,
                        const float* __restrict__ W1, const float* __restrict__ W2,
                        const float* __restrict__ C1, unsigned short* __restrict__ wbf) {
    int u = blockIdx.x * 256 + threadIdx.x;      // 0..24575
    int mat = u >> 11;
    int rr = u & 2047;
    int f = rr >> 6, lane = rr & 63;
    int kk = f >> 3, n8 = f & 7;
    int q = lane >> 4, l15 = lane & 15;
    int sm = mat / 3, w = mat - sm * 3;
    int t = best_t_for(tm, sm, nullptr);
    const float* src = (w == 0) ? W1 : (w == 1) ? W2 : C1;
    const float* sp = src + (((sm * 4 + t) << 14) + n8 * 16 + l15);
    int k0 = kk * 32 + q * 8;
    s16x8 o;
#pragma unroll
    for (int j = 0; j < 8; ++j) o[j] = (short)f2bf(sp[(k0 + j) * 128]);
    *(s16x8*)(wbf + (size_t)u * 8) = o;
}

// ================= k_fused v2: fused W1+C1 pass, slot-keyed swizzle =================
// M=128 rows/block, 512 blocks x 8 waves x 16 cols = one full 16-wave/CU generation.
// R6 residual costs attacked here:
//  (1) phases 1 and 3 shared the A operand but swept it twice -> FUSED: one pass computes
//      a1 += A*W1 and a3 += A*C1 (halves A-reads, perm lookups, loop overhead).
//  (2) gemmA read permuted rows with origin-keyed rot -> bank collisions (R5: 2.8M).
//      Now staging rotates row r by its READ SLOT (islot[r]&15), so reads use rot=l15<<3
//      (the proven conflict-free pattern); pad slots read a dedicated zero row (row 128).
//  (3) 4 barriers/block total.
// LDS: 33.0 KB A + 44 KB H + ~1.9 KB aux = 79.9 KB -> 2 blocks/CU.
__global__ __launch_bounds__(512, 4) void k_fused(
    const float* __restrict__ states, const float* __restrict__ scores,
    const int* __restrict__ type_ids, const float* __restrict__ tm,
    const float* __restrict__ b1g, const float* __restrict__ b2g,
    const float* __restrict__ c1g, const float* __restrict__ C2,
    const float* __restrict__ c2, const unsigned short* __restrict__ wbf,
    float* __restrict__ out_state, float* __restrict__ out_score,
    float* __restrict__ out_prob)
{
    __shared__ __align__(16) unsigned short Abuf[129 * 128];   // 32.25 KB (row 128 = zeros)
    __shared__ __align__(16) unsigned short Hbuf[176 * 128];   // 44 KB (11 segs max)
    __shared__ int permLds[176];                               // slot -> orig row (-1 = pad)
    __shared__ int islotLds[128];                              // orig row -> slot
    __shared__ float pSum[176];
    __shared__ int wcnt[2][4];

    const int t = threadIdx.x;
    const int gid0 = blockIdx.x * 128;
    const int lane = t & 63;
    const int wv = t >> 6;            // wave 0..7 -> 16-col slice
    const int l15 = lane & 15;
    const int quad = lane >> 4;
    const int myRow = t >> 2;         // staging: 4 threads/row, 128 rows
    const int q4 = t & 3;
    const int col = wv * 16 + l15;

    int stIdx4[4];
    float bmax[4];
#pragma unroll
    for (int s = 0; s < 4; ++s) stIdx4[s] = s * 4 + best_t_for(tm, s, &bmax[s]);

    if (t < 176) { permLds[t] = -1; pSum[t] = 0.f; }
    if (t >= 256 && t < 272)           // zero row 128 of Abuf (16 threads x 16 B)
        ((int4*)(Abuf + 128 * 128))[t - 256] = int4{0, 0, 0, 0};

    // ---- partition: waves 0,1 ballot their 64 rows ----
    int myty = 0, w2 = 0;
    unsigned long long msk = 0;
    if (t < 128) {
        w2 = t >> 6;
        myty = type_ids[gid0 + t];
#pragma unroll
        for (int sv = 0; sv < 4; ++sv) {
            unsigned long long mm = __ballot(myty == sv);
            if (myty == sv) msk = mm;
            if (lane == 0) wcnt[w2][sv] = (int)__popcll(mm);
        }
    }
    __syncthreads();   // B1: wcnt + inits visible

    // segment layout (redundant scalar compute in every thread)
    int nsA[4], sbA[4], G;
    {
        int sb = 0;
#pragma unroll
        for (int sv = 0; sv < 4; ++sv) {
            int c = wcnt[0][sv] + wcnt[1][sv];
            nsA[sv] = (c + 15) >> 4;
            sbA[sv] = sb;
            sb += nsA[sv];
        }
        G = sb;   // 4..11 segments
    }
    if (t < 128) {
        unsigned long long lt = (1ull << lane) - 1ull;
        int pos = sbA[myty] * 16 + ((w2 == 1) ? wcnt[0][myty] : 0) + (int)__popcll(msk & lt);
        permLds[pos] = t;
        islotLds[t] = pos;
    }
    __syncthreads();   // B2: perm/islot ready

    // ---- stage A: dense rows, SLOT-keyed rot -> conflict-free slot reads ----
    {
        const int rot = (islotLds[myRow] & 15) << 3;
        const float4* sp = (const float4*)(states + (size_t)(gid0 + myRow) * 128 + q4 * 32);
        float4 v[8];
#pragma unroll
        for (int i = 0; i < 8; ++i) v[i] = sp[i];
        unsigned short* dstRow = &Abuf[myRow * 128];
#pragma unroll
        for (int i = 0; i < 8; ++i) {
            int c = (q4 * 32 + i * 4 + rot) & 127;
            ushort4 o;
            o.x = f2bf(v[i].x); o.y = f2bf(v[i].y);
            o.z = f2bf(v[i].z); o.w = f2bf(v[i].w);
            *(ushort4*)(dstRow + c) = o;
        }
    }
    __syncthreads();   // B3: Abuf ready

    const unsigned short* __restrict__ wbase = wbf;
    s16x8 wfA[4], wfC[4];
    auto loadWf = [&](int ty, int m, s16x8 wf[4]) {
        const unsigned short* wb = wbase + ((size_t)ty * 3 + m) * 16384;
#pragma unroll
        for (int kk = 0; kk < 4; ++kk)
            wf[kk] = *(const s16x8*)(wb + (size_t)((kk * 8 + wv) * 64 + lane) * 8);
    };

    // ---- fused phase 1+3: per type, one pass over A computing W1- and C1-gemms ----
    for (int ty = 0; ty < 4; ++ty) {
        const int ns = nsA[ty];
        if (ns == 0) continue;                 // uniform across block
        const int sb = sbA[ty];
        const int si0 = stIdx4[ty];
        loadWf(ty, 0, wfA);
        loadWf(ty, 2, wfC);
        const float b1v = b1g[si0 * 128 + col];
        const float c1v = c1g[si0 * 128 + col];
        const float c2w = C2[si0 * 128 + col];
        for (int si = 0; si < ns; ++si) {
            const int seg = sb + si;
            int pRow = permLds[seg * 16 + l15];
            const unsigned short* ab = Abuf + ((pRow >= 0) ? pRow : 128) * 128;
            const int rotc = l15 << 3;
            f32x4 a1 = {0.f, 0.f, 0.f, 0.f};
            f32x4 a3 = {0.f, 0.f, 0.f, 0.f};
#pragma unroll
            for (int kk = 0; kk < 4; ++kk) {
                s16x8 af = *(const s16x8*)(ab + ((kk * 32 + quad * 8 + rotc) & 127));
                a1 = __builtin_amdgcn_mfma_f32_16x16x32_bf16(af, wfA[kk], a1, 0, 0, 0);
                a3 = __builtin_amdgcn_mfma_f32_16x16x32_bf16(af, wfC[kk], a3, 0, 0, 0);
            }
            // h -> Hbuf (slot-dense, slot-keyed swizzle)
#pragma unroll
            for (int r = 0; r < 4; ++r) {
                int row = seg * 16 + quad * 4 + r;
                float v = fmaxf(a1[r] + b1v, 0.f);
                Hbuf[row * 128 + ((col + ((row & 15) << 3)) & 127)] = f2bf(v);
            }
            // classifier partial: relu(a3+c1)*c2w, reduce over this wave's 16 cols
            float part[4];
#pragma unroll
            for (int r = 0; r < 4; ++r) part[r] = fmaxf(a3[r] + c1v, 0.f) * c2w;
#pragma unroll
            for (int off = 1; off < 16; off <<= 1)
#pragma unroll
                for (int r = 0; r < 4; ++r) part[r] += __shfl_xor(part[r], off, 64);
            if (l15 == 0) {
#pragma unroll
                for (int r = 0; r < 4; ++r)
                    atomicAdd(&pSum[seg * 16 + quad * 4 + r], part[r]);
            }
        }
    }
    __syncthreads();   // B4: Hbuf + pSum complete

    // ---- phase 2: y = h@W2 + b2 -> out_state scatter ----
    for (int ty = 0; ty < 4; ++ty) {
        const int ns = nsA[ty];
        if (ns == 0) continue;
        const int sb = sbA[ty];
        const int si0 = stIdx4[ty];
        loadWf(ty, 1, wfA);
        const float b2v = b2g[si0 * 128 + col];
        for (int si = 0; si < ns; ++si) {
            const int seg = sb + si;
            const unsigned short* hb = Hbuf + (seg * 16 + l15) * 128;
            f32x4 a = {0.f, 0.f, 0.f, 0.f};
#pragma unroll
            for (int kk = 0; kk < 4; ++kk) {
                s16x8 af = *(const s16x8*)(hb + ((kk * 32 + quad * 8 + (l15 << 3)) & 127));
                a = __builtin_amdgcn_mfma_f32_16x16x32_bf16(af, wfA[kk], a, 0, 0, 0);
            }
#pragma unroll
            for (int r = 0; r < 4; ++r) {
                int p = permLds[seg * 16 + quad * 4 + r];
                if (p >= 0) out_state[(size_t)(gid0 + p) * 128 + col] = a[r] + b2v;
            }
        }
    }

    // ---- epilogue: sigmoid, min, score + prob stores (pSum final since B4) ----
    if (t < G * 16) {
        int p = permLds[t];
        if (p >= 0) {
            int seg = t >> 4;
            int sty = (seg >= sbA[1] ? 1 : 0) + (seg >= sbA[2] ? 1 : 0) + (seg >= sbA[3] ? 1 : 0);
            float tot = pSum[t] + c2[stIdx4[sty]];
            float cls = 1.f / (1.f + expf(-tot));
            out_score[gid0 + p] = fminf(scores[gid0 + p], cls);
            out_prob[gid0 + p] = 1.f / (1.f + expf(-bmax[sty]));
        }
    }
}

extern "C" void kernel_launch(void* const* d_in, const int* in_sizes, int n_in,
                              void* d_out, int out_size, void* d_ws, size_t ws_size,
                              hipStream_t stream) {
    const float* states = (const float*)d_in[0];
    const float* scores = (const float*)d_in[1];
    const int*   type_ids = (const int*)d_in[2];
    const float* tm = (const float*)d_in[3];
    const float* W1 = (const float*)d_in[4];
    const float* b1 = (const float*)d_in[5];
    const float* W2 = (const float*)d_in[6];
    const float* b2 = (const float*)d_in[7];
    const float* C1 = (const float*)d_in[8];
    const float* c1 = (const float*)d_in[9];
    const float* C2 = (const float*)d_in[10];
    const float* c2 = (const float*)d_in[11];

    unsigned short* wbf = (unsigned short*)d_ws;            // 12 * 16384 bf16, frag-linear

    float* out_state = (float*)d_out;                       // N*128
    float* out_score = out_state + (size_t)Nn * 128;        // N
    float* out_prob  = out_score + Nn;                      // N

    k_prepw<<<96, 256, 0, stream>>>(tm, W1, W2, C1, wbf);
    k_fused<<<512, 512, 0, stream>>>(states, scores, type_ids, tm, b1, b2, c1,
        C2, c2, wbf, out_state, out_score, out_prob);
}